// Round 8
// baseline (232.446 us; speedup 1.0000x reference)
//
#include <hip/hip_runtime.h>
#include <hip/hip_fp16.h>

// ---------------------------------------------------------------------------
// Round-8: same pipeline as r7 (conv fp16 table ; minihist ; scan ; bin ;
// fused counting-sort + register gather), tuned for MLP/occupancy:
//   - buckets of 64 nodes (NB_SHIFT=6, NB=1563 blocks) -> 2x blocks, less tail
//   - accum blocks are 256 threads / 4 waves, wave owns 16 slots (r=i*4+w)
//   - slot inner loop unrolled 8-deep (8 outstanding 128B row loads/wave)
// Payload word0 = (dst&63)<<17 | src  (needs N <= 2^17), word1 = efeat.
// ---------------------------------------------------------------------------

#define NB_SHIFT 6
#define BNODES   64           // nodes per bucket
#define SRC_BITS 17
#define SRC_MASK ((1 << SRC_BITS) - 1)
#define BIN_S    4096         // edges per bin/hist block
#define BIN_T    512
#define ACC_T    256          // 4 waves
#define SGCAP    2048         // sort-chunk capacity (edges)
#define MAXNB    2048

__global__ void conv_half_kernel(const float* __restrict__ g, __half* __restrict__ h, int n) {
    int i = (blockIdx.x * blockDim.x + threadIdx.x) * 8;
    if (i + 7 < n) {
        float4 a = *(const float4*)(g + i);
        float4 b = *(const float4*)(g + i + 4);
        __half2 h0 = __floats2half2_rn(a.x, a.y);
        __half2 h1 = __floats2half2_rn(a.z, a.w);
        __half2 h2 = __floats2half2_rn(b.x, b.y);
        __half2 h3 = __floats2half2_rn(b.z, b.w);
        int4 o;
        o.x = *(int*)&h0; o.y = *(int*)&h1; o.z = *(int*)&h2; o.w = *(int*)&h3;
        *(int4*)(h + i) = o;
    } else {
        for (int k = i; k < n; ++k) h[k] = __float2half(g[k]);
    }
}

__global__ __launch_bounds__(BIN_T) void minihist_kernel(const int* __restrict__ dst,
                                                         int* __restrict__ counts,
                                                         int E, int NB) {
    __shared__ int cnt[MAXNB];
    int t = threadIdx.x;
    for (int i = t; i < MAXNB; i += BIN_T) cnt[i] = 0;
    __syncthreads();
    int e0 = blockIdx.x * BIN_S + t * 8;
    if (e0 + 7 < E) {
        int4 a = *(const int4*)(dst + e0);
        int4 b = *(const int4*)(dst + e0 + 4);
        atomicAdd(&cnt[a.x >> NB_SHIFT], 1);
        atomicAdd(&cnt[a.y >> NB_SHIFT], 1);
        atomicAdd(&cnt[a.z >> NB_SHIFT], 1);
        atomicAdd(&cnt[a.w >> NB_SHIFT], 1);
        atomicAdd(&cnt[b.x >> NB_SHIFT], 1);
        atomicAdd(&cnt[b.y >> NB_SHIFT], 1);
        atomicAdd(&cnt[b.z >> NB_SHIFT], 1);
        atomicAdd(&cnt[b.w >> NB_SHIFT], 1);
    } else {
        for (int k = e0; k < E; ++k) atomicAdd(&cnt[dst[k] >> NB_SHIFT], 1);
    }
    __syncthreads();
    for (int i = t; i < NB; i += BIN_T)
        if (cnt[i]) atomicAdd(&counts[i], cnt[i]);
}

// Exclusive scan over NB (<=2048) counters; one block, 1024 threads, 2/thread.
__global__ void scan_kernel(const int* __restrict__ counts,
                            int* __restrict__ goff, int* __restrict__ gcur,
                            int NB) {
    __shared__ int sh[1024];
    int t = threadIdx.x;
    int c0 = (2 * t     < NB) ? counts[2 * t]     : 0;
    int c1 = (2 * t + 1 < NB) ? counts[2 * t + 1] : 0;
    int s  = c0 + c1;
    sh[t] = s;
    __syncthreads();
    for (int o = 1; o < 1024; o <<= 1) {
        int u = (t >= o) ? sh[t - o] : 0;
        __syncthreads();
        sh[t] += u;
        __syncthreads();
    }
    int ex = sh[t] - s;
    if (2 * t < NB)     { goff[2 * t]     = ex;      gcur[2 * t]     = ex;      }
    if (2 * t + 1 < NB) { goff[2 * t + 1] = ex + c0; gcur[2 * t + 1] = ex + c0; }
    if (t == 1023) goff[NB] = sh[1023];
}

__global__ __launch_bounds__(BIN_T) void bin_kernel(const int* __restrict__ src,
                                                    const float* __restrict__ ef,
                                                    const int* __restrict__ dst,
                                                    int* __restrict__ gcur,
                                                    int2* __restrict__ gpay, int E) {
    __shared__ int cnt[MAXNB];              // 8 KB
    __shared__ int lbase[MAXNB];            // 8 KB
    __shared__ int pscan[BIN_T];            // 2 KB
    __shared__ int2 stage[BIN_S];           // 32 KB
    __shared__ unsigned short sbuck[BIN_S]; // 8 KB   (total 58 KB)

    int t = threadIdx.x;
    for (int i = t; i < MAXNB; i += BIN_T) cnt[i] = 0;
    __syncthreads();

    int e0 = blockIdx.x * BIN_S + t * 8;
    int dv[8], sv[8], bk[8], rk[8];
    float ev[8];

    if (e0 + 7 < E) {
        *(int4*)&dv[0]   = *(const int4*)(dst + e0);
        *(int4*)&dv[4]   = *(const int4*)(dst + e0 + 4);
        *(int4*)&sv[0]   = *(const int4*)(src + e0);
        *(int4*)&sv[4]   = *(const int4*)(src + e0 + 4);
        *(float4*)&ev[0] = *(const float4*)(ef + e0);
        *(float4*)&ev[4] = *(const float4*)(ef + e0 + 4);
#pragma unroll
        for (int k = 0; k < 8; ++k) {
            bk[k] = dv[k] >> NB_SHIFT;
            rk[k] = atomicAdd(&cnt[bk[k]], 1);
        }
    } else {
#pragma unroll
        for (int k = 0; k < 8; ++k) {
            if (e0 + k < E) {
                dv[k] = dst[e0 + k];
                sv[k] = src[e0 + k];
                ev[k] = ef[e0 + k];
                bk[k] = dv[k] >> NB_SHIFT;
                rk[k] = atomicAdd(&cnt[bk[k]], 1);
            } else {
                bk[k] = -1;
            }
        }
    }
    __syncthreads();

    // exclusive scan of cnt[0..MAXNB-1], 4 elems/thread
    int c0 = cnt[4 * t], c1 = cnt[4 * t + 1], c2 = cnt[4 * t + 2], c3 = cnt[4 * t + 3];
    int ts = c0 + c1 + c2 + c3;
    pscan[t] = ts;
    __syncthreads();
    for (int o = 1; o < BIN_T; o <<= 1) {
        int u = (t >= o) ? pscan[t - o] : 0;
        __syncthreads();
        pscan[t] += u;
        __syncthreads();
    }
    int ex = pscan[t] - ts;
    lbase[4 * t]     = ex;
    lbase[4 * t + 1] = ex + c0;
    lbase[4 * t + 2] = ex + c0 + c1;
    lbase[4 * t + 3] = ex + c0 + c1 + c2;
    __syncthreads();

    // stage ranked payloads
#pragma unroll
    for (int k = 0; k < 8; ++k) {
        if (bk[k] >= 0) {
            int pos = lbase[bk[k]] + rk[k];
            stage[pos] = make_int2(((dv[k] & (BNODES - 1)) << SRC_BITS) | sv[k],
                                   __float_as_int(ev[k]));
            sbuck[pos] = (unsigned short)bk[k];
        }
    }
    // global reserve per bucket; cnt[b] becomes (global_base - local_base)
    for (int i = t; i < MAXNB; i += BIN_T) {
        int c = cnt[i];
        cnt[i] = (c ? atomicAdd(&gcur[i], c) : 0) - lbase[i];
    }
    __syncthreads();

    // coalesced flush: consecutive stage entries -> consecutive global addrs
    int s_total = min(BIN_S, E - blockIdx.x * BIN_S);
    for (int i = t; i < s_total; i += BIN_T) {
        int b = sbuck[i];
        gpay[cnt[b] + i] = stage[i];
    }
}

// Fused counting-sort + register gather. One block per 64-node bucket,
// 4 waves; wave w owns slots r = i*4+w (i=0..15). Inner loop 8-deep MLP.
__global__ __launch_bounds__(ACC_T) void sortaccum_kernel(const __half* __restrict__ hg,
                                                          const int2* __restrict__ gpay,
                                                          const int* __restrict__ goff,
                                                          float* __restrict__ out,
                                                          int N) {
    __shared__ int  cnt[BNODES];
    __shared__ int  lbase[BNODES];
    __shared__ int  sbuf[BNODES];
    __shared__ int2 stage[SGCAP];   // 16 KB

    const int t    = threadIdx.x;
    const int b    = blockIdx.x;
    const int wave = t >> 6;
    const int lane = t & 63;
    const int lo   = goff[b];
    const int hi   = goff[b + 1];

    float acc[16];
    float eacc[16];
#pragma unroll
    for (int i = 0; i < 16; ++i) { acc[i] = 0.f; eacc[i] = 0.f; }

    for (int cbase = lo; cbase < hi; cbase += SGCAP) {
        const int csize = min(SGCAP, hi - cbase);

        if (t < BNODES) cnt[t] = 0;
        __syncthreads();

        // load + rank (8 payloads per thread, coalesced)
        int2 pv[8]; int rk[8]; int dr[8];
#pragma unroll
        for (int k = 0; k < 8; ++k) {
            int idx = t + k * ACC_T;
            dr[k] = -1;
            if (idx < csize) {
                pv[k] = gpay[cbase + idx];
                dr[k] = pv[k].x >> SRC_BITS;
                rk[k] = atomicAdd(&cnt[dr[k]], 1);
            }
        }
        __syncthreads();

        // exclusive scan of cnt[0..63] (all threads hit barriers)
        int v = (t < BNODES) ? cnt[t] : 0;
        if (t < BNODES) sbuf[t] = v;
        __syncthreads();
        for (int o = 1; o < BNODES; o <<= 1) {
            int u = (t < BNODES && t >= o) ? sbuf[t - o] : 0;
            __syncthreads();
            if (t < BNODES) sbuf[t] += u;
            __syncthreads();
        }
        if (t < BNODES) lbase[t] = sbuf[t] - v;
        __syncthreads();

        // place sorted
#pragma unroll
        for (int k = 0; k < 8; ++k)
            if (dr[k] >= 0) stage[lbase[dr[k]] + rk[k]] = pv[k];
        __syncthreads();

        // accumulate: wave w handles slots r = i*4 + wave
#pragma unroll
        for (int i = 0; i < 16; ++i) {
            const int r  = i * 4 + wave;
            const int s0 = lbase[r];
            const int c  = cnt[r];
            float a0 = 0.f, a1 = 0.f, a2 = 0.f, a3 = 0.f;
            float a4 = 0.f, a5 = 0.f, a6 = 0.f, a7 = 0.f;
            float e07 = 0.f;
            int j = 0;
            for (; j + 7 < c; j += 8) {
                int2 p0 = stage[s0 + j];     int2 p1 = stage[s0 + j + 1];
                int2 p2 = stage[s0 + j + 2]; int2 p3 = stage[s0 + j + 3];
                int2 p4 = stage[s0 + j + 4]; int2 p5 = stage[s0 + j + 5];
                int2 p6 = stage[s0 + j + 6]; int2 p7 = stage[s0 + j + 7];
                a0 += __half2float(hg[(size_t)(p0.x & SRC_MASK) * 64 + lane]);
                a1 += __half2float(hg[(size_t)(p1.x & SRC_MASK) * 64 + lane]);
                a2 += __half2float(hg[(size_t)(p2.x & SRC_MASK) * 64 + lane]);
                a3 += __half2float(hg[(size_t)(p3.x & SRC_MASK) * 64 + lane]);
                a4 += __half2float(hg[(size_t)(p4.x & SRC_MASK) * 64 + lane]);
                a5 += __half2float(hg[(size_t)(p5.x & SRC_MASK) * 64 + lane]);
                a6 += __half2float(hg[(size_t)(p6.x & SRC_MASK) * 64 + lane]);
                a7 += __half2float(hg[(size_t)(p7.x & SRC_MASK) * 64 + lane]);
                e07 += (__int_as_float(p0.y) + __int_as_float(p1.y) +
                        __int_as_float(p2.y) + __int_as_float(p3.y)) +
                       (__int_as_float(p4.y) + __int_as_float(p5.y) +
                        __int_as_float(p6.y) + __int_as_float(p7.y));
            }
            for (; j + 3 < c; j += 4) {
                int2 p0 = stage[s0 + j];     int2 p1 = stage[s0 + j + 1];
                int2 p2 = stage[s0 + j + 2]; int2 p3 = stage[s0 + j + 3];
                a0 += __half2float(hg[(size_t)(p0.x & SRC_MASK) * 64 + lane]);
                a1 += __half2float(hg[(size_t)(p1.x & SRC_MASK) * 64 + lane]);
                a2 += __half2float(hg[(size_t)(p2.x & SRC_MASK) * 64 + lane]);
                a3 += __half2float(hg[(size_t)(p3.x & SRC_MASK) * 64 + lane]);
                e07 += __int_as_float(p0.y) + __int_as_float(p1.y) +
                       __int_as_float(p2.y) + __int_as_float(p3.y);
            }
            for (; j < c; ++j) {
                int2 p = stage[s0 + j];
                a0  += __half2float(hg[(size_t)(p.x & SRC_MASK) * 64 + lane]);
                e07 += __int_as_float(p.y);
            }
            acc[i]  += ((a0 + a1) + (a2 + a3)) + ((a4 + a5) + (a6 + a7));
            eacc[i] += e07;
        }
        __syncthreads();   // stage/cnt reused next chunk
    }

    // write output rows once, near-linear
#pragma unroll
    for (int i = 0; i < 16; ++i) {
        const int r    = i * 4 + wave;
        const int node = b * BNODES + r;
        if (node < N) {
            out[(size_t)node * 65 + lane] = acc[i];
            if (lane == 0) out[(size_t)node * 65 + 64] = eacc[i];
        }
    }
}

// ---------------------- fallback (always correct) --------------------------

__global__ void atomic_fallback_kernel(const float* __restrict__ gemb,
                                       const float* __restrict__ efeat,
                                       const int* __restrict__ src,
                                       const int* __restrict__ dst,
                                       float* __restrict__ out, int E) {
    int eidx = blockIdx.x * 4 + (threadIdx.x >> 6);
    int lane = threadIdx.x & 63;
    if (eidx >= E) return;
    int s = src[eidx];
    int d = dst[eidx];
    float v = gemb[(size_t)s * 64 + lane];
    atomicAdd(&out[(size_t)d * 65 + lane], v);
    if (lane == 0) atomicAdd(&out[(size_t)d * 65 + 64], efeat[eidx]);
}

// ---------------------------------------------------------------------------

extern "C" void kernel_launch(void* const* d_in, const int* in_sizes, int n_in,
                              void* d_out, int out_size, void* d_ws, size_t ws_size,
                              hipStream_t stream) {
    const float* gemb  = (const float*)d_in[0];   // [N, 64]
    const float* efeat = (const float*)d_in[1];   // [E]
    const int*   src   = (const int*)d_in[2];     // [E]
    const int*   dst   = (const int*)d_in[3];     // [E]
    float*       out   = (float*)d_out;           // [N, 65]

    const int N  = in_sizes[0] / 64;
    const int E  = in_sizes[1];
    const int NB = (N + BNODES - 1) >> NB_SHIFT;

    auto aln = [](size_t x) { return (x + 15) & ~(size_t)15; };
    size_t off_counts = 0;
    size_t off_goff   = off_counts + aln((size_t)NB * 4);
    size_t off_gcur   = off_goff   + aln((size_t)(NB + 1) * 4);
    size_t off_gpay   = off_gcur   + aln((size_t)NB * 4);
    size_t off_hg     = off_gpay   + aln((size_t)E * 8);
    size_t needed     = off_hg     + (size_t)N * 64 * 2;

    if (N > (1 << SRC_BITS) || NB > MAXNB || ws_size < needed) {
        hipMemsetAsync(d_out, 0, (size_t)out_size * sizeof(float), stream);
        int blocks = (E + 3) / 4;
        atomic_fallback_kernel<<<blocks, 256, 0, stream>>>(gemb, efeat, src, dst, out, E);
        return;
    }

    char*   ws     = (char*)d_ws;
    int*    counts = (int*)(ws + off_counts);
    int*    goff   = (int*)(ws + off_goff);
    int*    gcur   = (int*)(ws + off_gcur);
    int2*   gpay   = (int2*)(ws + off_gpay);
    __half* hg     = (__half*)(ws + off_hg);

    hipMemsetAsync(counts, 0, (size_t)NB * 4, stream);

    int n_emb    = N * 64;
    int c_blocks = ((n_emb + 7) / 8 + 255) / 256;
    conv_half_kernel<<<c_blocks, 256, 0, stream>>>(gemb, hg, n_emb);

    int e_blocks = (E + BIN_S - 1) / BIN_S;
    minihist_kernel<<<e_blocks, BIN_T, 0, stream>>>(dst, counts, E, NB);
    scan_kernel<<<1, 1024, 0, stream>>>(counts, goff, gcur, NB);
    bin_kernel<<<e_blocks, BIN_T, 0, stream>>>(src, efeat, dst, gcur, gpay, E);
    sortaccum_kernel<<<NB, ACC_T, 0, stream>>>(hg, gpay, goff, out, N);
}

// Round 9
// 114.231 us; speedup vs baseline: 2.0349x; 2.0349x over previous
//
#include <hip/hip_runtime.h>
#include <hip/hip_fp16.h>

// ---------------------------------------------------------------------------
// Round-9: de-fused pipeline.
//   conv (fp32->fp16 table) ; minihist ; scan ; bin (edges -> 64-node bucket
//   windows, coalesced flush) ; bsort (bucket-local counting sort: writes are
//   random only within the ~6KB bucket window -> L2-combined; emits per-node
//   offsets) ; gather (r5's proven 54us kernel: 1 wave/node, 8-deep unroll,
//   fp16 rows, registers only, linear store).
// Payload word0 = (dst&63)<<17 | src  (needs N <= 2^17), word1 = efeat bits.
// ---------------------------------------------------------------------------

#define NB_SHIFT 6
#define BNODES   64           // nodes per bucket
#define SRC_BITS 17
#define SRC_MASK ((1 << SRC_BITS) - 1)
#define BIN_S    4096         // edges per bin/hist block
#define BIN_T    512
#define MAXNB    2048

__global__ void conv_half_kernel(const float* __restrict__ g, __half* __restrict__ h, int n) {
    int i = (blockIdx.x * blockDim.x + threadIdx.x) * 8;
    if (i + 7 < n) {
        float4 a = *(const float4*)(g + i);
        float4 b = *(const float4*)(g + i + 4);
        __half2 h0 = __floats2half2_rn(a.x, a.y);
        __half2 h1 = __floats2half2_rn(a.z, a.w);
        __half2 h2 = __floats2half2_rn(b.x, b.y);
        __half2 h3 = __floats2half2_rn(b.z, b.w);
        int4 o;
        o.x = *(int*)&h0; o.y = *(int*)&h1; o.z = *(int*)&h2; o.w = *(int*)&h3;
        *(int4*)(h + i) = o;
    } else {
        for (int k = i; k < n; ++k) h[k] = __float2half(g[k]);
    }
}

__global__ __launch_bounds__(BIN_T) void minihist_kernel(const int* __restrict__ dst,
                                                         int* __restrict__ counts,
                                                         int E, int NB) {
    __shared__ int cnt[MAXNB];
    int t = threadIdx.x;
    for (int i = t; i < MAXNB; i += BIN_T) cnt[i] = 0;
    __syncthreads();
    int e0 = blockIdx.x * BIN_S + t * 8;
    if (e0 + 7 < E) {
        int4 a = *(const int4*)(dst + e0);
        int4 b = *(const int4*)(dst + e0 + 4);
        atomicAdd(&cnt[a.x >> NB_SHIFT], 1);
        atomicAdd(&cnt[a.y >> NB_SHIFT], 1);
        atomicAdd(&cnt[a.z >> NB_SHIFT], 1);
        atomicAdd(&cnt[a.w >> NB_SHIFT], 1);
        atomicAdd(&cnt[b.x >> NB_SHIFT], 1);
        atomicAdd(&cnt[b.y >> NB_SHIFT], 1);
        atomicAdd(&cnt[b.z >> NB_SHIFT], 1);
        atomicAdd(&cnt[b.w >> NB_SHIFT], 1);
    } else {
        for (int k = e0; k < E; ++k) atomicAdd(&cnt[dst[k] >> NB_SHIFT], 1);
    }
    __syncthreads();
    for (int i = t; i < NB; i += BIN_T)
        if (cnt[i]) atomicAdd(&counts[i], cnt[i]);
}

// Exclusive scan over NB (<=2048) counters; one block, 1024 threads, 2/thread.
__global__ void scan_kernel(const int* __restrict__ counts,
                            int* __restrict__ goff, int* __restrict__ gcur,
                            int NB) {
    __shared__ int sh[1024];
    int t = threadIdx.x;
    int c0 = (2 * t     < NB) ? counts[2 * t]     : 0;
    int c1 = (2 * t + 1 < NB) ? counts[2 * t + 1] : 0;
    int s  = c0 + c1;
    sh[t] = s;
    __syncthreads();
    for (int o = 1; o < 1024; o <<= 1) {
        int u = (t >= o) ? sh[t - o] : 0;
        __syncthreads();
        sh[t] += u;
        __syncthreads();
    }
    int ex = sh[t] - s;
    if (2 * t < NB)     { goff[2 * t]     = ex;      gcur[2 * t]     = ex;      }
    if (2 * t + 1 < NB) { goff[2 * t + 1] = ex + c0; gcur[2 * t + 1] = ex + c0; }
    if (t == 1023) goff[NB] = sh[1023];
}

__global__ __launch_bounds__(BIN_T) void bin_kernel(const int* __restrict__ src,
                                                    const float* __restrict__ ef,
                                                    const int* __restrict__ dst,
                                                    int* __restrict__ gcur,
                                                    int2* __restrict__ gpay, int E) {
    __shared__ int cnt[MAXNB];              // 8 KB
    __shared__ int lbase[MAXNB];            // 8 KB
    __shared__ int pscan[BIN_T];            // 2 KB
    __shared__ int2 stage[BIN_S];           // 32 KB
    __shared__ unsigned short sbuck[BIN_S]; // 8 KB   (total 58 KB)

    int t = threadIdx.x;
    for (int i = t; i < MAXNB; i += BIN_T) cnt[i] = 0;
    __syncthreads();

    int e0 = blockIdx.x * BIN_S + t * 8;
    int dv[8], sv[8], bk[8], rk[8];
    float ev[8];

    if (e0 + 7 < E) {
        *(int4*)&dv[0]   = *(const int4*)(dst + e0);
        *(int4*)&dv[4]   = *(const int4*)(dst + e0 + 4);
        *(int4*)&sv[0]   = *(const int4*)(src + e0);
        *(int4*)&sv[4]   = *(const int4*)(src + e0 + 4);
        *(float4*)&ev[0] = *(const float4*)(ef + e0);
        *(float4*)&ev[4] = *(const float4*)(ef + e0 + 4);
#pragma unroll
        for (int k = 0; k < 8; ++k) {
            bk[k] = dv[k] >> NB_SHIFT;
            rk[k] = atomicAdd(&cnt[bk[k]], 1);
        }
    } else {
#pragma unroll
        for (int k = 0; k < 8; ++k) {
            if (e0 + k < E) {
                dv[k] = dst[e0 + k];
                sv[k] = src[e0 + k];
                ev[k] = ef[e0 + k];
                bk[k] = dv[k] >> NB_SHIFT;
                rk[k] = atomicAdd(&cnt[bk[k]], 1);
            } else {
                bk[k] = -1;
            }
        }
    }
    __syncthreads();

    // exclusive scan of cnt[0..MAXNB-1], 4 elems/thread
    int c0 = cnt[4 * t], c1 = cnt[4 * t + 1], c2 = cnt[4 * t + 2], c3 = cnt[4 * t + 3];
    int ts = c0 + c1 + c2 + c3;
    pscan[t] = ts;
    __syncthreads();
    for (int o = 1; o < BIN_T; o <<= 1) {
        int u = (t >= o) ? pscan[t - o] : 0;
        __syncthreads();
        pscan[t] += u;
        __syncthreads();
    }
    int ex = pscan[t] - ts;
    lbase[4 * t]     = ex;
    lbase[4 * t + 1] = ex + c0;
    lbase[4 * t + 2] = ex + c0 + c1;
    lbase[4 * t + 3] = ex + c0 + c1 + c2;
    __syncthreads();

    // stage ranked payloads
#pragma unroll
    for (int k = 0; k < 8; ++k) {
        if (bk[k] >= 0) {
            int pos = lbase[bk[k]] + rk[k];
            stage[pos] = make_int2(((dv[k] & (BNODES - 1)) << SRC_BITS) | sv[k],
                                   __float_as_int(ev[k]));
            sbuck[pos] = (unsigned short)bk[k];
        }
    }
    // global reserve per bucket; cnt[b] becomes (global_base - local_base)
    for (int i = t; i < MAXNB; i += BIN_T) {
        int c = cnt[i];
        cnt[i] = (c ? atomicAdd(&gcur[i], c) : 0) - lbase[i];
    }
    __syncthreads();

    // coalesced flush: consecutive stage entries -> consecutive global addrs
    int s_total = min(BIN_S, E - blockIdx.x * BIN_S);
    for (int i = t; i < s_total; i += BIN_T) {
        int b = sbuck[i];
        gpay[cnt[b] + i] = stage[i];
    }
}

// Bucket-local counting sort: one block per bucket. Two passes over the
// bucket window (~6KB, L2-resident). Emits node-sorted gpay2 + per-node
// offsets. Writes land inside the bucket window -> L2 write-combined.
__global__ __launch_bounds__(256) void bsort_kernel(const int2* __restrict__ gpay,
                                                    const int* __restrict__ goff,
                                                    int2* __restrict__ gpay2,
                                                    int* __restrict__ noff,
                                                    int N, int E) {
    __shared__ int cnt[BNODES];
    __shared__ int sbuf[BNODES];
    __shared__ int cur[BNODES];

    const int t  = threadIdx.x;
    const int b  = blockIdx.x;
    const int lo = goff[b];
    const int hi = goff[b + 1];

    if (t < BNODES) cnt[t] = 0;
    __syncthreads();

    // pass 1: per-node histogram
    for (int i = lo + t; i < hi; i += 256)
        atomicAdd(&cnt[gpay[i].x >> SRC_BITS], 1);
    __syncthreads();

    // exclusive scan of 64 counters (all threads hit barriers)
    int v = (t < BNODES) ? cnt[t] : 0;
    if (t < BNODES) sbuf[t] = v;
    __syncthreads();
    for (int o = 1; o < BNODES; o <<= 1) {
        int u = (t < BNODES && t >= o) ? sbuf[t - o] : 0;
        __syncthreads();
        if (t < BNODES) sbuf[t] += u;
        __syncthreads();
    }
    if (t < BNODES) {
        int base = lo + sbuf[t] - v;
        cur[t] = base;
        int node = b * BNODES + t;
        if (node <= N) noff[node] = base;   // node==N covered by empty slots
    }
    if (b == 0 && t == 0) noff[N] = E;      // in case N is a bucket multiple
    __syncthreads();

    // pass 2: place node-sorted
    for (int i = lo + t; i < hi; i += 256) {
        int2 p = gpay[i];
        int pos = atomicAdd(&cur[p.x >> SRC_BITS], 1);
        gpay2[pos] = p;
    }
}

// Gather: one wave per node, lane = feature, fp16 rows, 8-way unroll.
// (r5-proven pattern: 28 VGPR, ~66% occupancy.)
__global__ void gather_h_kernel(const __half* __restrict__ hg,
                                const int2* __restrict__ pack,
                                const int* __restrict__ noff,
                                float* __restrict__ out, int N) {
    int wid  = (blockIdx.x * blockDim.x + threadIdx.x) >> 6;
    int lane = threadIdx.x & 63;
    if (wid >= N) return;

    int beg = noff[wid];
    int end = noff[wid + 1];

    float a0 = 0.f, a1 = 0.f, a2 = 0.f, a3 = 0.f;
    float a4 = 0.f, a5 = 0.f, a6 = 0.f, a7 = 0.f;
    float ea = 0.f, eb = 0.f;
    int j = beg;
    for (; j + 7 < end; j += 8) {
        int2 v0 = pack[j];     int2 v1 = pack[j + 1];
        int2 v2 = pack[j + 2]; int2 v3 = pack[j + 3];
        int2 v4 = pack[j + 4]; int2 v5 = pack[j + 5];
        int2 v6 = pack[j + 6]; int2 v7 = pack[j + 7];
        a0 += __half2float(hg[(size_t)(v0.x & SRC_MASK) * 64 + lane]);
        a1 += __half2float(hg[(size_t)(v1.x & SRC_MASK) * 64 + lane]);
        a2 += __half2float(hg[(size_t)(v2.x & SRC_MASK) * 64 + lane]);
        a3 += __half2float(hg[(size_t)(v3.x & SRC_MASK) * 64 + lane]);
        a4 += __half2float(hg[(size_t)(v4.x & SRC_MASK) * 64 + lane]);
        a5 += __half2float(hg[(size_t)(v5.x & SRC_MASK) * 64 + lane]);
        a6 += __half2float(hg[(size_t)(v6.x & SRC_MASK) * 64 + lane]);
        a7 += __half2float(hg[(size_t)(v7.x & SRC_MASK) * 64 + lane]);
        ea += __int_as_float(v0.y) + __int_as_float(v1.y) +
              __int_as_float(v2.y) + __int_as_float(v3.y);
        eb += __int_as_float(v4.y) + __int_as_float(v5.y) +
              __int_as_float(v6.y) + __int_as_float(v7.y);
    }
    for (; j + 3 < end; j += 4) {
        int2 v0 = pack[j];     int2 v1 = pack[j + 1];
        int2 v2 = pack[j + 2]; int2 v3 = pack[j + 3];
        a0 += __half2float(hg[(size_t)(v0.x & SRC_MASK) * 64 + lane]);
        a1 += __half2float(hg[(size_t)(v1.x & SRC_MASK) * 64 + lane]);
        a2 += __half2float(hg[(size_t)(v2.x & SRC_MASK) * 64 + lane]);
        a3 += __half2float(hg[(size_t)(v3.x & SRC_MASK) * 64 + lane]);
        ea += __int_as_float(v0.y) + __int_as_float(v1.y) +
              __int_as_float(v2.y) + __int_as_float(v3.y);
    }
    for (; j < end; ++j) {
        int2 v = pack[j];
        a0 += __half2float(hg[(size_t)(v.x & SRC_MASK) * 64 + lane]);
        ea += __int_as_float(v.y);
    }
    out[(size_t)wid * 65 + lane] = ((a0 + a1) + (a2 + a3)) + ((a4 + a5) + (a6 + a7));
    if (lane == 0) out[(size_t)wid * 65 + 64] = ea + eb;
}

// ---------------------- fallback (always correct) --------------------------

__global__ void atomic_fallback_kernel(const float* __restrict__ gemb,
                                       const float* __restrict__ efeat,
                                       const int* __restrict__ src,
                                       const int* __restrict__ dst,
                                       float* __restrict__ out, int E) {
    int eidx = blockIdx.x * 4 + (threadIdx.x >> 6);
    int lane = threadIdx.x & 63;
    if (eidx >= E) return;
    int s = src[eidx];
    int d = dst[eidx];
    float v = gemb[(size_t)s * 64 + lane];
    atomicAdd(&out[(size_t)d * 65 + lane], v);
    if (lane == 0) atomicAdd(&out[(size_t)d * 65 + 64], efeat[eidx]);
}

// ---------------------------------------------------------------------------

extern "C" void kernel_launch(void* const* d_in, const int* in_sizes, int n_in,
                              void* d_out, int out_size, void* d_ws, size_t ws_size,
                              hipStream_t stream) {
    const float* gemb  = (const float*)d_in[0];   // [N, 64]
    const float* efeat = (const float*)d_in[1];   // [E]
    const int*   src   = (const int*)d_in[2];     // [E]
    const int*   dst   = (const int*)d_in[3];     // [E]
    float*       out   = (float*)d_out;           // [N, 65]

    const int N  = in_sizes[0] / 64;
    const int E  = in_sizes[1];
    const int NB = (N + BNODES - 1) >> NB_SHIFT;

    auto aln = [](size_t x) { return (x + 15) & ~(size_t)15; };
    size_t off_counts = 0;
    size_t off_goff   = off_counts + aln((size_t)NB * 4);
    size_t off_gcur   = off_goff   + aln((size_t)(NB + 1) * 4);
    size_t off_noff   = off_gcur   + aln((size_t)NB * 4);
    size_t off_gpay   = off_noff   + aln((size_t)(N + 1) * 4);
    size_t off_gpay2  = off_gpay   + aln((size_t)E * 8);
    size_t off_hg     = off_gpay2  + aln((size_t)E * 8);
    size_t needed     = off_hg     + (size_t)N * 64 * 2;

    if (N > (1 << SRC_BITS) || NB > MAXNB || ws_size < needed) {
        hipMemsetAsync(d_out, 0, (size_t)out_size * sizeof(float), stream);
        int blocks = (E + 3) / 4;
        atomic_fallback_kernel<<<blocks, 256, 0, stream>>>(gemb, efeat, src, dst, out, E);
        return;
    }

    char*   ws     = (char*)d_ws;
    int*    counts = (int*)(ws + off_counts);
    int*    goff   = (int*)(ws + off_goff);
    int*    gcur   = (int*)(ws + off_gcur);
    int*    noff   = (int*)(ws + off_noff);
    int2*   gpay   = (int2*)(ws + off_gpay);
    int2*   gpay2  = (int2*)(ws + off_gpay2);
    __half* hg     = (__half*)(ws + off_hg);

    hipMemsetAsync(counts, 0, (size_t)NB * 4, stream);

    int n_emb    = N * 64;
    int c_blocks = ((n_emb + 7) / 8 + 255) / 256;
    conv_half_kernel<<<c_blocks, 256, 0, stream>>>(gemb, hg, n_emb);

    int e_blocks = (E + BIN_S - 1) / BIN_S;
    minihist_kernel<<<e_blocks, BIN_T, 0, stream>>>(dst, counts, E, NB);
    scan_kernel<<<1, 1024, 0, stream>>>(counts, goff, gcur, NB);
    bin_kernel<<<e_blocks, BIN_T, 0, stream>>>(src, efeat, dst, gcur, gpay, E);
    bsort_kernel<<<NB, 256, 0, stream>>>(gpay, goff, gpay2, noff, N, E);

    int g_blocks = (N + 3) / 4;
    gather_h_kernel<<<g_blocks, 256, 0, stream>>>(hg, gpay2, noff, out, N);
}

// Round 10
// 110.099 us; speedup vs baseline: 2.1113x; 1.0375x over previous
//
#include <hip/hip_runtime.h>
#include <hip/hip_fp16.h>

// ---------------------------------------------------------------------------
// Round-10: r9 pipeline with prep-chain cuts.
//   convhist (fused fp32->fp16 table conv + bucket minihist) ; scan ; bin
//   (wave-shfl scans) ; bsort (bucket-local counting sort, emits 4B src-only
//   sorted array + per-node offsets + writes out[:,64] itself) ; gather
//   (1 wave/node, 8-deep unroll, fp16 rows, 64 features only, linear store).
// Payload in gpay: word0 = (dst&63)<<17 | src  (needs N <= 2^17), word1=efeat.
// ---------------------------------------------------------------------------

#define NB_SHIFT 6
#define BNODES   64           // nodes per bucket
#define SRC_BITS 17
#define SRC_MASK ((1 << SRC_BITS) - 1)
#define BIN_S    4096         // edges per bin/hist block
#define BIN_T    512
#define MAXNB    2048

// Fused: blocks [0, c_blocks) convert the table fp32->fp16 (4096 elems each);
// blocks [c_blocks, ...) histogram dst into NB bucket counts.
__global__ __launch_bounds__(BIN_T) void convhist_kernel(const float* __restrict__ g,
                                                         __half* __restrict__ h,
                                                         int n_emb, int c_blocks,
                                                         const int* __restrict__ dst,
                                                         int* __restrict__ counts,
                                                         int E, int NB) {
    __shared__ int cnt[MAXNB];
    int t = threadIdx.x;

    if (blockIdx.x < c_blocks) {
        int i = (blockIdx.x * BIN_T + t) * 8;
        if (i + 7 < n_emb) {
            float4 a = *(const float4*)(g + i);
            float4 b = *(const float4*)(g + i + 4);
            __half2 h0 = __floats2half2_rn(a.x, a.y);
            __half2 h1 = __floats2half2_rn(a.z, a.w);
            __half2 h2 = __floats2half2_rn(b.x, b.y);
            __half2 h3 = __floats2half2_rn(b.z, b.w);
            int4 o;
            o.x = *(int*)&h0; o.y = *(int*)&h1; o.z = *(int*)&h2; o.w = *(int*)&h3;
            *(int4*)(h + i) = o;
        } else {
            for (int k = i; k < n_emb; ++k) h[k] = __float2half(g[k]);
        }
        return;
    }

    int hb = blockIdx.x - c_blocks;
    for (int i = t; i < MAXNB; i += BIN_T) cnt[i] = 0;
    __syncthreads();
    int e0 = hb * BIN_S + t * 8;
    if (e0 + 7 < E) {
        int4 a = *(const int4*)(dst + e0);
        int4 b = *(const int4*)(dst + e0 + 4);
        atomicAdd(&cnt[a.x >> NB_SHIFT], 1);
        atomicAdd(&cnt[a.y >> NB_SHIFT], 1);
        atomicAdd(&cnt[a.z >> NB_SHIFT], 1);
        atomicAdd(&cnt[a.w >> NB_SHIFT], 1);
        atomicAdd(&cnt[b.x >> NB_SHIFT], 1);
        atomicAdd(&cnt[b.y >> NB_SHIFT], 1);
        atomicAdd(&cnt[b.z >> NB_SHIFT], 1);
        atomicAdd(&cnt[b.w >> NB_SHIFT], 1);
    } else {
        for (int k = e0; k < E; ++k) atomicAdd(&cnt[dst[k] >> NB_SHIFT], 1);
    }
    __syncthreads();
    for (int i = t; i < NB; i += BIN_T)
        if (cnt[i]) atomicAdd(&counts[i], cnt[i]);
}

// Exclusive scan over NB (<=2048) counters; one block, 1024 threads, 2/thread.
__global__ void scan_kernel(const int* __restrict__ counts,
                            int* __restrict__ goff, int* __restrict__ gcur,
                            int NB) {
    __shared__ int sh[1024];
    int t = threadIdx.x;
    int c0 = (2 * t     < NB) ? counts[2 * t]     : 0;
    int c1 = (2 * t + 1 < NB) ? counts[2 * t + 1] : 0;
    int s  = c0 + c1;
    sh[t] = s;
    __syncthreads();
    for (int o = 1; o < 1024; o <<= 1) {
        int u = (t >= o) ? sh[t - o] : 0;
        __syncthreads();
        sh[t] += u;
        __syncthreads();
    }
    int ex = sh[t] - s;
    if (2 * t < NB)     { goff[2 * t]     = ex;      gcur[2 * t]     = ex;      }
    if (2 * t + 1 < NB) { goff[2 * t + 1] = ex + c0; gcur[2 * t + 1] = ex + c0; }
    if (t == 1023) goff[NB] = sh[1023];
}

__global__ __launch_bounds__(BIN_T) void bin_kernel(const int* __restrict__ src,
                                                    const float* __restrict__ ef,
                                                    const int* __restrict__ dst,
                                                    int* __restrict__ gcur,
                                                    int2* __restrict__ gpay, int E) {
    __shared__ int cnt[MAXNB];              // 8 KB
    __shared__ int lbase[MAXNB];            // 8 KB
    __shared__ int wsum[8];
    __shared__ int wbase[8];
    __shared__ int2 stage[BIN_S];           // 32 KB
    __shared__ unsigned short sbuck[BIN_S]; // 8 KB

    const int t    = threadIdx.x;
    const int lane = t & 63;
    const int wv   = t >> 6;

    for (int i = t; i < MAXNB; i += BIN_T) cnt[i] = 0;
    __syncthreads();

    int e0 = blockIdx.x * BIN_S + t * 8;
    int dv[8], sv[8], bk[8], rk[8];
    float ev[8];

    if (e0 + 7 < E) {
        *(int4*)&dv[0]   = *(const int4*)(dst + e0);
        *(int4*)&dv[4]   = *(const int4*)(dst + e0 + 4);
        *(int4*)&sv[0]   = *(const int4*)(src + e0);
        *(int4*)&sv[4]   = *(const int4*)(src + e0 + 4);
        *(float4*)&ev[0] = *(const float4*)(ef + e0);
        *(float4*)&ev[4] = *(const float4*)(ef + e0 + 4);
#pragma unroll
        for (int k = 0; k < 8; ++k) {
            bk[k] = dv[k] >> NB_SHIFT;
            rk[k] = atomicAdd(&cnt[bk[k]], 1);
        }
    } else {
#pragma unroll
        for (int k = 0; k < 8; ++k) {
            if (e0 + k < E) {
                dv[k] = dst[e0 + k];
                sv[k] = src[e0 + k];
                ev[k] = ef[e0 + k];
                bk[k] = dv[k] >> NB_SHIFT;
                rk[k] = atomicAdd(&cnt[bk[k]], 1);
            } else {
                bk[k] = -1;
            }
        }
    }
    __syncthreads();

    // exclusive scan of cnt[0..MAXNB-1], 4/thread: wave shfl scan + cross-wave
    int c0 = cnt[4 * t], c1 = cnt[4 * t + 1], c2 = cnt[4 * t + 2], c3 = cnt[4 * t + 3];
    int ts = c0 + c1 + c2 + c3;
    int incl = ts;
#pragma unroll
    for (int o = 1; o < 64; o <<= 1) {
        int u = __shfl_up(incl, o);
        if (lane >= o) incl += u;
    }
    if (lane == 63) wsum[wv] = incl;
    __syncthreads();
    if (t < 8) {
        int v = wsum[t];
        int inc = v;
#pragma unroll
        for (int o = 1; o < 8; o <<= 1) {
            int u = __shfl_up(inc, o);
            if (t >= o) inc += u;
        }
        wbase[t] = inc - v;
    }
    __syncthreads();
    int ex = wbase[wv] + (incl - ts);
    lbase[4 * t]     = ex;
    lbase[4 * t + 1] = ex + c0;
    lbase[4 * t + 2] = ex + c0 + c1;
    lbase[4 * t + 3] = ex + c0 + c1 + c2;
    __syncthreads();

    // stage ranked payloads
#pragma unroll
    for (int k = 0; k < 8; ++k) {
        if (bk[k] >= 0) {
            int pos = lbase[bk[k]] + rk[k];
            stage[pos] = make_int2(((dv[k] & (BNODES - 1)) << SRC_BITS) | sv[k],
                                   __float_as_int(ev[k]));
            sbuck[pos] = (unsigned short)bk[k];
        }
    }
    // global reserve per bucket; cnt[b] becomes (global_base - local_base)
    for (int i = t; i < MAXNB; i += BIN_T) {
        int c = cnt[i];
        cnt[i] = (c ? atomicAdd(&gcur[i], c) : 0) - lbase[i];
    }
    __syncthreads();

    // coalesced flush: consecutive stage entries -> consecutive global addrs
    int s_total = min(BIN_S, E - blockIdx.x * BIN_S);
    for (int i = t; i < s_total; i += BIN_T) {
        int b = sbuck[i];
        gpay[cnt[b] + i] = stage[i];
    }
}

// Bucket-local counting sort. One block per bucket (two passes over the
// ~6KB L2-resident window). Emits node-sorted 4B src array + per-node
// offsets, accumulates efeat per node in LDS and writes out[:,64] directly.
__global__ __launch_bounds__(256) void bsort_kernel(const int2* __restrict__ gpay,
                                                    const int* __restrict__ goff,
                                                    int* __restrict__ gsrc2,
                                                    int* __restrict__ noff,
                                                    float* __restrict__ out,
                                                    int N, int E) {
    __shared__ int   cnt[BNODES];
    __shared__ int   cur[BNODES];
    __shared__ float esum[BNODES];

    const int t  = threadIdx.x;
    const int b  = blockIdx.x;
    const int lo = goff[b];
    const int hi = goff[b + 1];

    if (t < BNODES) { cnt[t] = 0; esum[t] = 0.f; }
    __syncthreads();

    // pass 1: per-node histogram
    for (int i = lo + t; i < hi; i += 256)
        atomicAdd(&cnt[gpay[i].x >> SRC_BITS], 1);
    __syncthreads();

    // wave-0 shfl exclusive scan of the 64 counters
    if (t < 64) {
        int v = cnt[t];
        int inc = v;
#pragma unroll
        for (int o = 1; o < 64; o <<= 1) {
            int u = __shfl_up(inc, o);
            if (t >= o) inc += u;
        }
        int base = lo + inc - v;
        cur[t] = base;
        int node = b * BNODES + t;
        if (node <= N) noff[node] = base;
    }
    if (b == 0 && t == 0) noff[N] = E;
    __syncthreads();

    // pass 2: place node-sorted srcs; accumulate efeat per node
    for (int i = lo + t; i < hi; i += 256) {
        int2 p = gpay[i];
        int  r = p.x >> SRC_BITS;
        int pos = atomicAdd(&cur[r], 1);
        gsrc2[pos] = p.x & SRC_MASK;
        atomicAdd(&esum[r], __int_as_float(p.y));
    }
    __syncthreads();

    // write the efeat column
    if (t < 64) {
        int node = b * BNODES + t;
        if (node < N) out[(size_t)node * 65 + 64] = esum[t];
    }
}

// Gather: one wave per node, lane = feature, fp16 rows, 8-way unroll.
// src-only 4B entries; no e-accumulation (bsort wrote column 64).
__global__ void gather_h_kernel(const __half* __restrict__ hg,
                                const int* __restrict__ gs,
                                const int* __restrict__ noff,
                                float* __restrict__ out, int N) {
    int wid  = (blockIdx.x * blockDim.x + threadIdx.x) >> 6;
    int lane = threadIdx.x & 63;
    if (wid >= N) return;

    int beg = noff[wid];
    int end = noff[wid + 1];

    float a0 = 0.f, a1 = 0.f, a2 = 0.f, a3 = 0.f;
    float a4 = 0.f, a5 = 0.f, a6 = 0.f, a7 = 0.f;
    int j = beg;
    for (; j + 7 < end; j += 8) {
        int s0 = gs[j];     int s1 = gs[j + 1];
        int s2 = gs[j + 2]; int s3 = gs[j + 3];
        int s4 = gs[j + 4]; int s5 = gs[j + 5];
        int s6 = gs[j + 6]; int s7 = gs[j + 7];
        a0 += __half2float(hg[(size_t)s0 * 64 + lane]);
        a1 += __half2float(hg[(size_t)s1 * 64 + lane]);
        a2 += __half2float(hg[(size_t)s2 * 64 + lane]);
        a3 += __half2float(hg[(size_t)s3 * 64 + lane]);
        a4 += __half2float(hg[(size_t)s4 * 64 + lane]);
        a5 += __half2float(hg[(size_t)s5 * 64 + lane]);
        a6 += __half2float(hg[(size_t)s6 * 64 + lane]);
        a7 += __half2float(hg[(size_t)s7 * 64 + lane]);
    }
    for (; j + 3 < end; j += 4) {
        int s0 = gs[j];     int s1 = gs[j + 1];
        int s2 = gs[j + 2]; int s3 = gs[j + 3];
        a0 += __half2float(hg[(size_t)s0 * 64 + lane]);
        a1 += __half2float(hg[(size_t)s1 * 64 + lane]);
        a2 += __half2float(hg[(size_t)s2 * 64 + lane]);
        a3 += __half2float(hg[(size_t)s3 * 64 + lane]);
    }
    for (; j < end; ++j) {
        a0 += __half2float(hg[(size_t)gs[j] * 64 + lane]);
    }
    out[(size_t)wid * 65 + lane] = ((a0 + a1) + (a2 + a3)) + ((a4 + a5) + (a6 + a7));
}

// ---------------------- fallback (always correct) --------------------------

__global__ void atomic_fallback_kernel(const float* __restrict__ gemb,
                                       const float* __restrict__ efeat,
                                       const int* __restrict__ src,
                                       const int* __restrict__ dst,
                                       float* __restrict__ out, int E) {
    int eidx = blockIdx.x * 4 + (threadIdx.x >> 6);
    int lane = threadIdx.x & 63;
    if (eidx >= E) return;
    int s = src[eidx];
    int d = dst[eidx];
    float v = gemb[(size_t)s * 64 + lane];
    atomicAdd(&out[(size_t)d * 65 + lane], v);
    if (lane == 0) atomicAdd(&out[(size_t)d * 65 + 64], efeat[eidx]);
}

// ---------------------------------------------------------------------------

extern "C" void kernel_launch(void* const* d_in, const int* in_sizes, int n_in,
                              void* d_out, int out_size, void* d_ws, size_t ws_size,
                              hipStream_t stream) {
    const float* gemb  = (const float*)d_in[0];   // [N, 64]
    const float* efeat = (const float*)d_in[1];   // [E]
    const int*   src   = (const int*)d_in[2];     // [E]
    const int*   dst   = (const int*)d_in[3];     // [E]
    float*       out   = (float*)d_out;           // [N, 65]

    const int N  = in_sizes[0] / 64;
    const int E  = in_sizes[1];
    const int NB = (N + BNODES - 1) >> NB_SHIFT;

    auto aln = [](size_t x) { return (x + 15) & ~(size_t)15; };
    size_t off_counts = 0;
    size_t off_goff   = off_counts + aln((size_t)NB * 4);
    size_t off_gcur   = off_goff   + aln((size_t)(NB + 1) * 4);
    size_t off_noff   = off_gcur   + aln((size_t)NB * 4);
    size_t off_gpay   = off_noff   + aln((size_t)(N + 1) * 4);
    size_t off_gsrc2  = off_gpay   + aln((size_t)E * 8);
    size_t off_hg     = off_gsrc2  + aln((size_t)E * 4);
    size_t needed     = off_hg     + (size_t)N * 64 * 2;

    if (N > (1 << SRC_BITS) || NB > MAXNB || ws_size < needed) {
        hipMemsetAsync(d_out, 0, (size_t)out_size * sizeof(float), stream);
        int blocks = (E + 3) / 4;
        atomic_fallback_kernel<<<blocks, 256, 0, stream>>>(gemb, efeat, src, dst, out, E);
        return;
    }

    char*   ws     = (char*)d_ws;
    int*    counts = (int*)(ws + off_counts);
    int*    goff   = (int*)(ws + off_goff);
    int*    gcur   = (int*)(ws + off_gcur);
    int*    noff   = (int*)(ws + off_noff);
    int2*   gpay   = (int2*)(ws + off_gpay);
    int*    gsrc2  = (int*)(ws + off_gsrc2);
    __half* hg     = (__half*)(ws + off_hg);

    hipMemsetAsync(counts, 0, (size_t)NB * 4, stream);

    int n_emb    = N * 64;
    int c_blocks = (n_emb + BIN_T * 8 - 1) / (BIN_T * 8);
    int h_blocks = (E + BIN_S - 1) / BIN_S;
    convhist_kernel<<<c_blocks + h_blocks, BIN_T, 0, stream>>>(
        gemb, hg, n_emb, c_blocks, dst, counts, E, NB);

    scan_kernel<<<1, 1024, 0, stream>>>(counts, goff, gcur, NB);
    bin_kernel<<<h_blocks, BIN_T, 0, stream>>>(src, efeat, dst, gcur, gpay, E);
    bsort_kernel<<<NB, 256, 0, stream>>>(gpay, goff, gsrc2, noff, out, N, E);

    int g_blocks = (N + 3) / 4;
    gather_h_kernel<<<g_blocks, 256, 0, stream>>>(hg, gsrc2, noff, out, N);
}